// Round 8
// baseline (282.454 us; speedup 1.0000x reference)
//
#include <hip/hip_runtime.h>
#include <math.h>

#define DM 512
#define LSEQ 2048
#define BATCH 4
#define NH 8
#define EH 64
#define DFF 2048
#define MTOK (BATCH*LSEQ)   // 8192
#define QKVW 1536
// 0.125 (1/sqrt(64)) * log2(e), folded into Q so softmax uses raw exp2
#define QSCL 0.18033688011112042f

using short8  = __attribute__((ext_vector_type(8))) short;
using floatx4 = __attribute__((ext_vector_type(4))) float;

__device__ __forceinline__ short f2b(float f) {           // RNE fp32->bf16
    unsigned u = __float_as_uint(f);
    return (short)((u + 0x7FFFu + ((u >> 16) & 1u)) >> 16);
}
__device__ __forceinline__ float b2f(short s) {
    return __uint_as_float(((unsigned)(unsigned short)s) << 16);
}
// pack two fp32 -> bf16x2 (round-half-up)
__device__ __forceinline__ unsigned pack2bf(float lo, float hi) {
    return __builtin_amdgcn_perm(__float_as_uint(hi) + 0x8000u,
                                 __float_as_uint(lo) + 0x8000u, 0x07060302u);
}
// tanh-form GELU (max |err| vs exact-erf GELU ~1e-3)
__device__ __forceinline__ float gelu_tanh(float v) {
    float v2 = v * v;
    float y  = v * fmaf(0.0356774081f, v2, 0.7978845608f);
    float e  = __builtin_amdgcn_exp2f(y * 2.885390082f);
    float r  = __builtin_amdgcn_rcpf(e + 1.0f);
    return v * (1.0f - r);
}
__device__ __forceinline__ void load_lds16(const short* g, short* l) {
    __builtin_amdgcn_global_load_lds(
        (const __attribute__((address_space(1))) void*)g,
        (__attribute__((address_space(3))) void*)l, 16, 0, 0);
}
#define MFMA_BF16(a, b, c) __builtin_amdgcn_mfma_f32_16x16x32_bf16(a, b, c, 0, 0, 0)

// ---------------------------------------------------------------------------
// Prep mega-kernel: 6 weight transposes (fp32->bf16), x fp32->bf16, qkv bias.
// ---------------------------------------------------------------------------
__global__ __launch_bounds__(256) void prep_kernel(
    const float* __restrict__ Wq, const float* __restrict__ Wk,
    const float* __restrict__ Wv, const float* __restrict__ Wo,
    const float* __restrict__ W1, const float* __restrict__ W2,
    const float* __restrict__ x,
    const float* __restrict__ bq, const float* __restrict__ bk,
    const float* __restrict__ bv,
    short* __restrict__ Wqkvt, short* __restrict__ Wot,
    short* __restrict__ W1t, short* __restrict__ W2t,
    short* __restrict__ xb, float* __restrict__ bqkv)
{
    __shared__ float t[64][65];
    const int bid = blockIdx.x;
    const int tid = threadIdx.x;

    if (bid >= 2880) {                    // bias fuse
        #pragma unroll
        for (int j = 0; j < 6; ++j) {
            const int i = j * 256 + tid;
            bqkv[i] = (i < 512) ? bq[i] : (i < 1024 ? bk[i - 512] : bv[i - 1024]);
        }
        return;
    }
    if (bid >= 832) {                     // x cvt, 8 elems/thread
        const long i = ((long)(bid - 832) * 256 + tid) * 8;
        float4 a = *(const float4*)(x + i);
        float4 b = *(const float4*)(x + i + 4);
        short tt[8] = { f2b(a.x), f2b(a.y), f2b(a.z), f2b(a.w),
                        f2b(b.x), f2b(b.y), f2b(b.z), f2b(b.w) };
        *(float4*)(xb + i) = *(float4*)tt;
        return;
    }
    const float* src; short* dst; int C, R, bx, by;
    if (bid < 256) {
        const int w = bid >> 6, sub = bid & 63;
        src = (w == 0) ? Wq : (w == 1) ? Wk : Wv;
        dst = Wqkvt + (long)w * 262144;
        R = 512; C = 512; bx = sub & 7; by = sub >> 3;
    } else if (bid < 320) {
        const int sub = bid - 256;
        src = Wo; dst = Wot; R = 512; C = 512; bx = sub & 7; by = sub >> 3;
    } else if (bid < 576) {
        const int sub = bid - 320;
        src = W1; dst = W1t; R = 512; C = 2048; bx = sub & 31; by = sub >> 5;
    } else {
        const int sub = bid - 576;
        src = W2; dst = W2t; R = 2048; C = 512; bx = sub & 7; by = sub >> 3;
    }
    const int r0 = by * 64, c0 = bx * 64;
    const int r = tid >> 2, cs = (tid & 3) * 16;
    const float* ip = src + (long)(r0 + r) * C + c0 + cs;
    #pragma unroll
    for (int i = 0; i < 4; ++i) {
        float4 v = *(const float4*)(ip + i * 4);
        t[r][cs + i*4 + 0] = v.x; t[r][cs + i*4 + 1] = v.y;
        t[r][cs + i*4 + 2] = v.z; t[r][cs + i*4 + 3] = v.w;
    }
    __syncthreads();
    short tmp[16];
    #pragma unroll
    for (int j = 0; j < 16; ++j) tmp[j] = f2b(t[cs + j][r]);
    short* op = dst + (long)(c0 + r) * R + r0 + cs;
    *(float4*)op       = *(float4*)&tmp[0];
    *(float4*)(op + 8) = *(float4*)&tmp[8];
}

// ---------------------------------------------------------------------------
// bf16 MFMA GEMM: C = A @ Bt^T + bias. 128 x TN tile, KB-wide K-iter (32/64),
// double-buffered global_load_lds staging, ONE barrier per K-iter.
// QKV mode: q cols scaled by QSCL; v cols packed-b64 into Vt[b][h][e][l].
// ---------------------------------------------------------------------------
template<int TN, int KB, int DO_GELU, int QKV>
__global__ __launch_bounds__(256, (KB == 32 ? 4 : 2)) void mfma_gemm(
    const short* __restrict__ A, const short* __restrict__ Bt,
    const float* __restrict__ bias, short* __restrict__ C,
    short* __restrict__ VtOut, int M, int N, int K, int lda, int ldc)
{
    constexpr int NJ  = TN / 32;          // j-tiles per wave
    constexpr int KS  = KB / 32;          // k-steps per iter
    constexpr int RPI = 1024 / (KB * 2);  // rows per 1KB staging instr
    constexpr int AI  = 128 / RPI / 4;    // A staging instrs per wave
    constexpr int BI  = TN / RPI / 4;     // B staging instrs per wave
    __shared__ short As[2][128][KB];
    __shared__ short Bs[2][TN][KB];

    const int tid  = threadIdx.x;
    const int wave = tid >> 6;
    const int lane = tid & 63;
    const int qd   = lane >> 4;
    const int sl   = lane & 15;
    const int m0 = blockIdx.y * 128;
    const int n0 = blockIdx.x * TN;
    const int wm = (wave & 1) * 64;
    const int wn = (wave >> 1) * (TN / 2);
    const int lr = lane / (KB / 8);       // staging row within RPI group
    const int lc = (lane % (KB / 8)) * 8; // staging short offset

    floatx4 acc[4][NJ];
    const floatx4 fz = {0.f, 0.f, 0.f, 0.f};
    #pragma unroll
    for (int i = 0; i < 4; ++i)
        #pragma unroll
        for (int j = 0; j < NJ; ++j) acc[i][j] = fz;

    const short* Abase = A  + (long)m0 * lda + lc;
    const short* Bbase = Bt + (long)n0 * K   + lc;

    #pragma unroll
    for (int it = 0; it < AI; ++it) {
        const int row0 = (wave * AI + it) * RPI;
        load_lds16(Abase + (long)(row0 + lr) * lda, &As[0][row0][0]);
    }
    #pragma unroll
    for (int it = 0; it < BI; ++it) {
        const int row0 = (wave * BI + it) * RPI;
        load_lds16(Bbase + (long)(row0 + lr) * K, &Bs[0][row0][0]);
    }

    const int NIT = K / KB;
    for (int kit = 0; kit < NIT; ++kit) {
        const int cur = kit & 1;
        __syncthreads();                  // staging(cur) landed; buf(1-cur) free
        if (kit + 1 < NIT) {
            const int nk = (kit + 1) * KB;
            #pragma unroll
            for (int it = 0; it < AI; ++it) {
                const int row0 = (wave * AI + it) * RPI;
                load_lds16(Abase + (long)(row0 + lr) * lda + nk, &As[1 - cur][row0][0]);
            }
            #pragma unroll
            for (int it = 0; it < BI; ++it) {
                const int row0 = (wave * BI + it) * RPI;
                load_lds16(Bbase + (long)(row0 + lr) * K + nk, &Bs[1 - cur][row0][0]);
            }
        }
        #pragma unroll
        for (int s = 0; s < KS; ++s) {
            short8 af[4], bf[NJ];
            #pragma unroll
            for (int t = 0; t < 4; ++t)
                af[t] = *(const short8*)&As[cur][wm + t*16 + sl][s*32 + qd*8];
            #pragma unroll
            for (int t = 0; t < NJ; ++t)
                bf[t] = *(const short8*)&Bs[cur][wn + t*16 + sl][s*32 + qd*8];
            #pragma unroll
            for (int i = 0; i < 4; ++i)
                #pragma unroll
                for (int j = 0; j < NJ; ++j)
                    acc[i][j] = MFMA_BF16(af[i], bf[j], acc[i][j]);
        }
    }

    #pragma unroll
    for (int j = 0; j < NJ; ++j) {
        const int col = n0 + wn + j*16 + sl;
        const float bvs = bias[col];
        #pragma unroll
        for (int i = 0; i < 4; ++i) {
            float v[4];
            #pragma unroll
            for (int r = 0; r < 4; ++r) {
                float tv = acc[i][j][r] + bvs;
                if (DO_GELU) tv = gelu_tanh(tv);
                v[r] = tv;
            }
            const int row0 = m0 + wm + i*16 + qd*4;
            if (QKV) {
                if (col < 1024) {
                    const float s = (col < 512) ? QSCL : 1.0f;
                    #pragma unroll
                    for (int r = 0; r < 4; ++r)
                        C[(long)(row0 + r) * 1024 + col] = f2b(v[r] * s);
                } else {
                    const int e = col - 1024;
                    const int b_ = row0 >> 11, l0 = row0 & 2047;
                    uint2 w;
                    w.x = pack2bf(v[0], v[1]);
                    w.y = pack2bf(v[2], v[3]);
                    *(uint2*)&VtOut[(((long)(b_*8 + (e >> 6))) * 64 + (e & 63)) * 2048 + l0] = w;
                }
            } else {
                #pragma unroll
                for (int r = 0; r < 4; ++r)
                    C[(long)(row0 + r) * ldc + col] = f2b(v[r]);
            }
        }
    }
}

// ---------------------------------------------------------------------------
// Flash attention, bf16 MFMA, S^T formulation, 8-wave (512-thread) blocks.
// Block = (b,h,128-q tile), 8 waves x 16 queries, 64 keys/iter, grid 512
// (bid&7=h for XCD locality). Waves 0-3 stage K, 4-7 stage V (double-buffered
// LDS via global_load_lds, ONE barrier/iter). S^T = K.Q^T -> exp2 -> v_perm
// pack -> 4 ds_write_b64 P^T writes/wave, read back as b128 A-frags for PV.
// No-max softmax (scale folded into Q). ~50 KB LDS -> 2 blocks/CU =
// 16 waves/CU (4/SIMD) for latency hiding.
// ---------------------------------------------------------------------------
__global__ __launch_bounds__(512, 4) void mfma_attn(
    const short* __restrict__ QK, const short* __restrict__ VtG,
    short* __restrict__ O)
{
    __shared__ short Ks[2][2][64][32];   // [buf][e-half][key][e32]  16 KB
    __shared__ short Vs[2][2][64][32];   // [buf][k-half][e][key32]  16 KB
    __shared__ short PT[8][16][68];      // per-wave Q-stage / P^T[query][key] 17 KB

    const int tid  = threadIdx.x;
    const int wave = tid >> 6;           // 0..7
    const int lane = tid & 63;
    const int qd   = lane >> 4;
    const int sl   = lane & 15;
    const int kw   = wave & 3;           // staging row-group
    const int srow = lane >> 2;
    const int scol = (lane & 3) * 8;
    const bool is_v = wave >= 4;

    const int bid = blockIdx.x;
    const int h  = bid & 7;
    const int b  = (bid >> 3) & 3;
    const int qt = bid >> 5;             // 0..15
    const int tok0 = b * LSEQ;
    const int q0 = qt * 128;

    const short* Kbase = QK + (long)tok0 * 1024 + 512 + h * EH
                         + (long)(kw*16 + srow) * 1024 + scol;
    const short* Vbase = VtG + ((long)(b * NH + h)) * EH * 2048
                         + (long)(kw*16 + srow) * 2048 + scol;

    {   // Q stage (wave-local): wave's 16 query rows x 64 shorts into PT strip
        const int qr = lane >> 2;            // 0..15
        const int qc = (lane & 3) * 16;
        const short* qp = QK + (long)(tok0 + q0 + wave*16 + qr) * 1024 + h * EH + qc;
        short* dp = &PT[wave][qr][qc];
        *(float4*)dp       = *(const float4*)qp;
        *(float4*)(dp + 8) = *(const float4*)(qp + 8);
    }
    short8 aq[2];
    #pragma unroll
    for (int ks = 0; ks < 2; ++ks)
        aq[ks] = *(const short8*)&PT[wave][sl][ks*32 + qd*8];

    float l_i = 0.f;
    floatx4 oacc[4];
    const floatx4 fz = {0.f, 0.f, 0.f, 0.f};
    #pragma unroll
    for (int t = 0; t < 4; ++t) oacc[t] = fz;

    // prologue: stage kt=0 into buf 0 (waves 0-3 -> K, 4-7 -> V)
    if (!is_v) {
        #pragma unroll
        for (int p = 0; p < 2; ++p) load_lds16(Kbase + p*32, &Ks[0][p][kw*16][0]);
    } else {
        #pragma unroll
        for (int p = 0; p < 2; ++p) load_lds16(Vbase + p*32, &Vs[0][p][kw*16][0]);
    }

    for (int kt = 0; kt < 32; ++kt) {
        const int cur = kt & 1;
        __syncthreads();                 // staging(cur) landed; buf(1-cur) free
        if (kt + 1 < 32) {
            if (!is_v) {
                #pragma unroll
                for (int p = 0; p < 2; ++p)
                    load_lds16(Kbase + (long)(kt+1)*64*1024 + p*32, &Ks[1 - cur][p][kw*16][0]);
            } else {
                #pragma unroll
                for (int p = 0; p < 2; ++p)
                    load_lds16(Vbase + (kt+1)*64 + p*32, &Vs[1 - cur][p][kw*16][0]);
            }
        }

        // S^T[key][q] = K . Q^T
        floatx4 sT[4];
        #pragma unroll
        for (int t = 0; t < 4; ++t) sT[t] = fz;
        #pragma unroll
        for (int ks = 0; ks < 2; ++ks)
            #pragma unroll
            for (int t = 0; t < 4; ++t) {
                short8 ak = *(const short8*)&Ks[cur][ks][t*16 + sl][qd * 8];
                sT[t] = MFMA_BF16(ak, aq[ks], sT[t]);
            }

        // exp2, pack consecutive keys to bf16x2, write P^T rows (b64)
        #pragma unroll
        for (int t = 0; t < 4; ++t) {
            const float p0 = __builtin_amdgcn_exp2f(sT[t][0]);
            const float p1 = __builtin_amdgcn_exp2f(sT[t][1]);
            const float p2 = __builtin_amdgcn_exp2f(sT[t][2]);
            const float p3 = __builtin_amdgcn_exp2f(sT[t][3]);
            l_i += (p0 + p1) + (p2 + p3);
            uint2 w;
            w.x = pack2bf(p0, p1);
            w.y = pack2bf(p2, p3);
            *(uint2*)&PT[wave][sl][t*16 + qd*4] = w;
        }

        // O += P V
        #pragma unroll
        for (int ks = 0; ks < 2; ++ks) {
            short8 ap = *(const short8*)&PT[wave][sl][ks*32 + qd*8];
            #pragma unroll
            for (int t = 0; t < 4; ++t) {
                short8 bv = *(const short8*)&Vs[cur][ks][t*16 + sl][qd * 8];
                oacc[t] = MFMA_BF16(ap, bv, oacc[t]);
            }
        }
    }

    // reduce l over qd groups; pick per output row
    l_i += __shfl_xor(l_i, 16);
    l_i += __shfl_xor(l_i, 32);
    float linv[4];
    #pragma unroll
    for (int r = 0; r < 4; ++r)
        linv[r] = 1.0f / __shfl(l_i, qd*4 + r, 64);

    #pragma unroll
    for (int t = 0; t < 4; ++t)
        #pragma unroll
        for (int r = 0; r < 4; ++r) {
            const int row = tok0 + q0 + wave*16 + qd*4 + r;
            const int col = h * EH + t*16 + sl;
            O[(long)row * DM + col] = f2b(oacc[t][r] * linv[r]);
        }
}

// ---------------------------------------------------------------------------
// out = LN(X + R) * g + beta. X fp32 or bf16, R bf16, out bf16 or fp32.
// ---------------------------------------------------------------------------
template<int X_BF16, int OUT_F32>
__global__ __launch_bounds__(256) void add_ln_kernel(
    const void* __restrict__ Xv, const short* __restrict__ R,
    const float* __restrict__ g, const float* __restrict__ beta,
    void* __restrict__ outv)
{
    const int row = blockIdx.x;
    const int tid = threadIdx.x;
    float x0, x1;
    if (X_BF16) {
        const short* xp = (const short*)Xv + (long)row * DM;
        x0 = b2f(xp[tid]); x1 = b2f(xp[tid + 256]);
    } else {
        const float* xp = (const float*)Xv + (long)row * DM;
        x0 = xp[tid]; x1 = xp[tid + 256];
    }
    const short* rp = R + (long)row * DM;
    const float v0 = x0 + b2f(rp[tid]);
    const float v1 = x1 + b2f(rp[tid + 256]);
    float s = v0 + v1, sq = v0*v0 + v1*v1;
    #pragma unroll
    for (int o = 32; o > 0; o >>= 1) {
        s  += __shfl_down(s, o);
        sq += __shfl_down(sq, o);
    }
    __shared__ float ss[4], ssq[4];
    const int wid = tid >> 6, lane = tid & 63;
    if (lane == 0) { ss[wid] = s; ssq[wid] = sq; }
    __syncthreads();
    const float S  = ss[0] + ss[1] + ss[2] + ss[3];
    const float SQ = ssq[0] + ssq[1] + ssq[2] + ssq[3];
    const float mean = S * (1.0f / DM);
    const float var  = SQ * (1.0f / DM) - mean * mean;
    const float rstd = rsqrtf(var + 1e-5f);
    const float o0 = (v0 - mean) * rstd * g[tid] + beta[tid];
    const float o1 = (v1 - mean) * rstd * g[tid + 256] + beta[tid + 256];
    if (OUT_F32) {
        float* op = (float*)outv + (long)row * DM;
        op[tid] = o0; op[tid + 256] = o1;
    } else {
        short* op = (short*)outv + (long)row * DM;
        op[tid] = f2b(o0); op[tid + 256] = f2b(o1);
    }
}

// ---------------------------------------------------------------------------
extern "C" void kernel_launch(void* const* d_in, const int* in_sizes, int n_in,
                              void* d_out, int out_size, void* d_ws, size_t ws_size,
                              hipStream_t stream)
{
    const float* x   = (const float*)d_in[0];
    const float* Wq  = (const float*)d_in[1];
    const float* bq  = (const float*)d_in[2];
    const float* Wk  = (const float*)d_in[3];
    const float* bk  = (const float*)d_in[4];
    const float* Wv  = (const float*)d_in[5];
    const float* bv  = (const float*)d_in[6];
    const float* Wo  = (const float*)d_in[7];
    const float* bo  = (const float*)d_in[8];
    const float* W1  = (const float*)d_in[9];
    const float* b1  = (const float*)d_in[10];
    const float* W2  = (const float*)d_in[11];
    const float* b2  = (const float*)d_in[12];
    const float* g1  = (const float*)d_in[13];
    const float* be1 = (const float*)d_in[14];
    const float* g2  = (const float*)d_in[15];
    const float* be2 = (const float*)d_in[16];
    float* out = (float*)d_out;

    // workspace layout (~56.6 MB)
    short* ws    = (short*)d_ws;
    short* Wqkvt = ws;                         // [1536][512]
    short* Wot   = Wqkvt + 786432;             // [512][512]
    short* W1t   = Wot + 262144;               // [2048][512]
    short* W2t   = W1t + 1048576;              // [512][2048]
    float* bqkv  = (float*)(W2t + 1048576);    // [1536] fp32
    short* xb    = (short*)(bqkv + 1536);      // [8192][512]  (later x1b)
    short* qk    = xb + 4194304;               // [8192][1024] q|k
    short* VtG   = qk + 8388608;               // [b][h][64][2048]
    short* Ob    = VtG + 4194304;              // [8192][512]
    short* res   = Ob + 4194304;               // [8192][512]  attn_out / ffn_out
    short* hbuf  = qk;                         // [8192][2048] overlays qk|VtG|Ob

    const dim3 blk(256);

    prep_kernel<<<dim3(2881), blk, 0, stream>>>(
        Wq, Wk, Wv, Wo, W1, W2, x, bq, bk, bv,
        Wqkvt, Wot, W1t, W2t, xb, bqkv);

    // QKV: [8192,512] @ [512,1536] -> qk + VtG (q scaled by QSCL), BK=64
    mfma_gemm<128, 64, 0, 1><<<dim3(12, 64), blk, 0, stream>>>(
        xb, Wqkvt, bqkv, qk, VtG, MTOK, QKVW, DM, DM, 0);

    mfma_attn<<<dim3(512), dim3(512), 0, stream>>>(qk, VtG, Ob);

    // Wo: [8192,512] @ [512,512] -> res (bf16), TN=64, BK=64
    mfma_gemm<64, 64, 0, 0><<<dim3(8, 64), blk, 0, stream>>>(
        Ob, Wot, bo, res, nullptr, MTOK, DM, DM, DM, DM);

    // x1b = LN(x + res)  (bf16)
    add_ln_kernel<0, 0><<<dim3(MTOK), blk, 0, stream>>>(x, res, g1, be1, xb);

    // FFN1: [8192,512] @ [512,2048], GELU -> hbuf, BK=32 (control)
    mfma_gemm<128, 32, 1, 0><<<dim3(16, 64), blk, 0, stream>>>(
        xb, W1t, b1, hbuf, nullptr, MTOK, DFF, DM, DM, DFF);

    // FFN2: [8192,2048] @ [2048,512] -> res, TN=64, BK=64
    mfma_gemm<64, 64, 0, 0><<<dim3(8, 64), blk, 0, stream>>>(
        hbuf, W2t, b2, res, nullptr, MTOK, DM, DFF, DFF, DM);

    // out = LN(x1b + res)  (fp32)
    add_ln_kernel<1, 1><<<dim3(MTOK), blk, 0, stream>>>(xb, res, g2, be2, out);
}

// Round 9
// 270.556 us; speedup vs baseline: 1.0440x; 1.0440x over previous
//
#include <hip/hip_runtime.h>
#include <math.h>

#define DM 512
#define LSEQ 2048
#define BATCH 4
#define NH 8
#define EH 64
#define DFF 2048
#define MTOK (BATCH*LSEQ)   // 8192
#define QKVW 1536
// 0.125 (1/sqrt(64)) * log2(e), folded into Q so softmax uses raw exp2
#define QSCL 0.18033688011112042f

using short8  = __attribute__((ext_vector_type(8))) short;
using floatx4 = __attribute__((ext_vector_type(4))) float;

__device__ __forceinline__ short f2b(float f) {           // RNE fp32->bf16
    unsigned u = __float_as_uint(f);
    return (short)((u + 0x7FFFu + ((u >> 16) & 1u)) >> 16);
}
__device__ __forceinline__ float b2f(short s) {
    return __uint_as_float(((unsigned)(unsigned short)s) << 16);
}
// pack two fp32 -> bf16x2 (round-half-up)
__device__ __forceinline__ unsigned pack2bf(float lo, float hi) {
    return __builtin_amdgcn_perm(__float_as_uint(hi) + 0x8000u,
                                 __float_as_uint(lo) + 0x8000u, 0x07060302u);
}
// tanh-form GELU (max |err| vs exact-erf GELU ~1e-3)
__device__ __forceinline__ float gelu_tanh(float v) {
    float v2 = v * v;
    float y  = v * fmaf(0.0356774081f, v2, 0.7978845608f);
    float e  = __builtin_amdgcn_exp2f(y * 2.885390082f);
    float r  = __builtin_amdgcn_rcpf(e + 1.0f);
    return v * (1.0f - r);
}
__device__ __forceinline__ void load_lds16(const short* g, short* l) {
    __builtin_amdgcn_global_load_lds(
        (const __attribute__((address_space(1))) void*)g,
        (__attribute__((address_space(3))) void*)l, 16, 0, 0);
}
#define MFMA_BF16(a, b, c) __builtin_amdgcn_mfma_f32_16x16x32_bf16(a, b, c, 0, 0, 0)

// ---------------------------------------------------------------------------
// Prep mega-kernel: 6 weight transposes (fp32->bf16), x fp32->bf16, qkv bias.
// ---------------------------------------------------------------------------
__global__ __launch_bounds__(256) void prep_kernel(
    const float* __restrict__ Wq, const float* __restrict__ Wk,
    const float* __restrict__ Wv, const float* __restrict__ Wo,
    const float* __restrict__ W1, const float* __restrict__ W2,
    const float* __restrict__ x,
    const float* __restrict__ bq, const float* __restrict__ bk,
    const float* __restrict__ bv,
    short* __restrict__ Wqkvt, short* __restrict__ Wot,
    short* __restrict__ W1t, short* __restrict__ W2t,
    short* __restrict__ xb, float* __restrict__ bqkv)
{
    __shared__ float t[64][65];
    const int bid = blockIdx.x;
    const int tid = threadIdx.x;

    if (bid >= 2880) {                    // bias fuse
        #pragma unroll
        for (int j = 0; j < 6; ++j) {
            const int i = j * 256 + tid;
            bqkv[i] = (i < 512) ? bq[i] : (i < 1024 ? bk[i - 512] : bv[i - 1024]);
        }
        return;
    }
    if (bid >= 832) {                     // x cvt, 8 elems/thread
        const long i = ((long)(bid - 832) * 256 + tid) * 8;
        float4 a = *(const float4*)(x + i);
        float4 b = *(const float4*)(x + i + 4);
        short tt[8] = { f2b(a.x), f2b(a.y), f2b(a.z), f2b(a.w),
                        f2b(b.x), f2b(b.y), f2b(b.z), f2b(b.w) };
        *(float4*)(xb + i) = *(float4*)tt;
        return;
    }
    const float* src; short* dst; int C, R, bx, by;
    if (bid < 256) {
        const int w = bid >> 6, sub = bid & 63;
        src = (w == 0) ? Wq : (w == 1) ? Wk : Wv;
        dst = Wqkvt + (long)w * 262144;
        R = 512; C = 512; bx = sub & 7; by = sub >> 3;
    } else if (bid < 320) {
        const int sub = bid - 256;
        src = Wo; dst = Wot; R = 512; C = 512; bx = sub & 7; by = sub >> 3;
    } else if (bid < 576) {
        const int sub = bid - 320;
        src = W1; dst = W1t; R = 512; C = 2048; bx = sub & 31; by = sub >> 5;
    } else {
        const int sub = bid - 576;
        src = W2; dst = W2t; R = 2048; C = 512; bx = sub & 7; by = sub >> 3;
    }
    const int r0 = by * 64, c0 = bx * 64;
    const int r = tid >> 2, cs = (tid & 3) * 16;
    const float* ip = src + (long)(r0 + r) * C + c0 + cs;
    #pragma unroll
    for (int i = 0; i < 4; ++i) {
        float4 v = *(const float4*)(ip + i * 4);
        t[r][cs + i*4 + 0] = v.x; t[r][cs + i*4 + 1] = v.y;
        t[r][cs + i*4 + 2] = v.z; t[r][cs + i*4 + 3] = v.w;
    }
    __syncthreads();
    short tmp[16];
    #pragma unroll
    for (int j = 0; j < 16; ++j) tmp[j] = f2b(t[cs + j][r]);
    short* op = dst + (long)(c0 + r) * R + r0 + cs;
    *(float4*)op       = *(float4*)&tmp[0];
    *(float4*)(op + 8) = *(float4*)&tmp[8];
}

// ---------------------------------------------------------------------------
// bf16 MFMA GEMM: C = A @ Bt^T + bias. 128 x TN tile, BK=32, double-buffered
// global_load_lds staging, ONE barrier per K-iter. A,B,C bf16.
// QKV mode: q cols scaled by QSCL; v cols packed-b64 into Vt[b][h][e][l].
// ---------------------------------------------------------------------------
template<int TN, int DO_GELU, int QKV>
__global__ __launch_bounds__(256, 4) void mfma_gemm(
    const short* __restrict__ A, const short* __restrict__ Bt,
    const float* __restrict__ bias, short* __restrict__ C,
    short* __restrict__ VtOut, int M, int N, int K, int lda, int ldc)
{
    constexpr int NJ = TN / 32;
    constexpr int NB = TN / 64;
    __shared__ short As[2][128][32];
    __shared__ short Bs[2][TN][32];

    const int tid  = threadIdx.x;
    const int wave = tid >> 6;
    const int lane = tid & 63;
    const int qd   = lane >> 4;
    const int sl   = lane & 15;
    const int m0 = blockIdx.y * 128;
    const int n0 = blockIdx.x * TN;
    const int wm = (wave & 1) * 64;
    const int wn = (wave >> 1) * (TN / 2);
    const int srow = lane >> 2;
    const int scol = (lane & 3) * 8;

    floatx4 acc[4][NJ];
    const floatx4 fz = {0.f, 0.f, 0.f, 0.f};
    #pragma unroll
    for (int i = 0; i < 4; ++i)
        #pragma unroll
        for (int j = 0; j < NJ; ++j) acc[i][j] = fz;

    const short* Abase = A  + (long)m0 * lda + scol;
    const short* Bbase = Bt + (long)n0 * K   + scol;

    #pragma unroll
    for (int it = 0; it < 2; ++it) {
        const int rg = wave * 2 + it;
        load_lds16(Abase + (long)(rg*16 + srow) * lda, &As[0][rg * 16][0]);
    }
    #pragma unroll
    for (int it = 0; it < NB; ++it) {
        const int rg = wave * NB + it;
        load_lds16(Bbase + (long)(rg*16 + srow) * K, &Bs[0][rg * 16][0]);
    }

    const int NIT = K / 32;
    for (int kit = 0; kit < NIT; ++kit) {
        const int cur = kit & 1;
        __syncthreads();
        if (kit + 1 < NIT) {
            const int nk = (kit + 1) * 32;
            #pragma unroll
            for (int it = 0; it < 2; ++it) {
                const int rg = wave * 2 + it;
                load_lds16(Abase + (long)(rg*16 + srow) * lda + nk, &As[1 - cur][rg * 16][0]);
            }
            #pragma unroll
            for (int it = 0; it < NB; ++it) {
                const int rg = wave * NB + it;
                load_lds16(Bbase + (long)(rg*16 + srow) * K + nk, &Bs[1 - cur][rg * 16][0]);
            }
        }
        short8 af[4], bf[NJ];
        #pragma unroll
        for (int t = 0; t < 4; ++t)
            af[t] = *(const short8*)&As[cur][wm + t*16 + sl][qd * 8];
        #pragma unroll
        for (int t = 0; t < NJ; ++t)
            bf[t] = *(const short8*)&Bs[cur][wn + t*16 + sl][qd * 8];
        #pragma unroll
        for (int i = 0; i < 4; ++i)
            #pragma unroll
            for (int j = 0; j < NJ; ++j)
                acc[i][j] = MFMA_BF16(af[i], bf[j], acc[i][j]);
    }

    #pragma unroll
    for (int j = 0; j < NJ; ++j) {
        const int col = n0 + wn + j*16 + sl;
        const float bvs = bias[col];
        #pragma unroll
        for (int i = 0; i < 4; ++i) {
            float v[4];
            #pragma unroll
            for (int r = 0; r < 4; ++r) {
                float tv = acc[i][j][r] + bvs;
                if (DO_GELU) tv = gelu_tanh(tv);
                v[r] = tv;
            }
            const int row0 = m0 + wm + i*16 + qd*4;
            if (QKV) {
                if (col < 1024) {
                    const float s = (col < 512) ? QSCL : 1.0f;
                    #pragma unroll
                    for (int r = 0; r < 4; ++r)
                        C[(long)(row0 + r) * 1024 + col] = f2b(v[r] * s);
                } else {
                    const int e = col - 1024;
                    const int b_ = row0 >> 11, l0 = row0 & 2047;
                    uint2 w;
                    w.x = pack2bf(v[0], v[1]);
                    w.y = pack2bf(v[2], v[3]);
                    *(uint2*)&VtOut[(((long)(b_*8 + (e >> 6))) * 64 + (e & 63)) * 2048 + l0] = w;
                }
            } else {
                #pragma unroll
                for (int r = 0; r < 4; ++r)
                    C[(long)(row0 + r) * ldc + col] = f2b(v[r]);
            }
        }
    }
}

// ---------------------------------------------------------------------------
// Flash attention, bf16 MFMA, S^T formulation, SPLIT-K over keys.
// Block = (b, h, 256-q tile, key-half): 8 waves x 32 queries (2 subtiles),
// 64 keys/iter x 16 iters. Grid 512 (bid&7=h for XCD locality), 2 blocks/CU
// = 16 waves/CU. Waves 0-3 stage K, 4-7 stage V (dbuf LDS via
// global_load_lds, ONE barrier/iter). Each K/V fragment read feeds 2 MFMAs
// (q-subtile sharing). No-max softmax => partials exactly additive: emit
// UNNORMALIZED partial O (bf16) + per-(row,head) l (fp32); attn_combine
// normalizes. LDS 68 KB.
// ---------------------------------------------------------------------------
__global__ __launch_bounds__(512, 2) void mfma_attn(
    const short* __restrict__ QK, const short* __restrict__ VtG,
    short* __restrict__ Op0, short* __restrict__ Op1, float* __restrict__ lbuf)
{
    __shared__ short Ks[2][2][64][32];   // [buf][e-half][key][e32]  16 KB
    __shared__ short Vs[2][2][64][32];   // [buf][k-half][e][key32]  16 KB
    __shared__ short PT[8][32][72];      // per-wave Q-stage / P^T[q][key] 36 KB

    const int tid  = threadIdx.x;
    const int wave = tid >> 6;           // 0..7
    const int lane = tid & 63;
    const int qd   = lane >> 4;
    const int sl   = lane & 15;
    const int kw   = wave & 3;
    const int srow = lane >> 2;
    const int scol = (lane & 3) * 8;
    const bool is_v = wave >= 4;

    const int bid = blockIdx.x;
    const int h   = bid & 7;
    const int b   = (bid >> 3) & 3;
    const int qt  = (bid >> 5) & 7;      // 0..7
    const int ksp = bid >> 8;            // 0..1 key-split half
    const int tok0 = b * LSEQ;
    const int q0 = qt * 256;
    const int kt0 = ksp * 16;

    const short* Kbase = QK + (long)tok0 * 1024 + 512 + h * EH
                         + (long)(kt0*64 + kw*16 + srow) * 1024 + scol;
    const short* Vbase = VtG + ((long)(b * NH + h)) * EH * 2048
                         + (long)(kw*16 + srow) * 2048 + kt0*64 + scol;

    {   // Q stage (wave-local): wave's 32 query rows x 64 shorts into PT strip
        const int qr = lane >> 1;            // 0..31
        const int qc = (lane & 1) * 32;
        const short* qp = QK + (long)(tok0 + q0 + wave*32 + qr) * 1024 + h * EH + qc;
        short* dp = &PT[wave][qr][qc];
        *(float4*)dp        = *(const float4*)qp;
        *(float4*)(dp + 8)  = *(const float4*)(qp + 8);
        *(float4*)(dp + 16) = *(const float4*)(qp + 16);
        *(float4*)(dp + 24) = *(const float4*)(qp + 24);
    }
    short8 aq[2][2];
    #pragma unroll
    for (int q2 = 0; q2 < 2; ++q2)
        #pragma unroll
        for (int ks = 0; ks < 2; ++ks)
            aq[q2][ks] = *(const short8*)&PT[wave][q2*16 + sl][ks*32 + qd*8];

    float l_i[2] = {0.f, 0.f};
    floatx4 oacc[2][4];
    const floatx4 fz = {0.f, 0.f, 0.f, 0.f};
    #pragma unroll
    for (int q2 = 0; q2 < 2; ++q2)
        #pragma unroll
        for (int t = 0; t < 4; ++t) oacc[q2][t] = fz;

    // prologue: stage kt=0 into buf 0 (waves 0-3 -> K, 4-7 -> V)
    if (!is_v) {
        #pragma unroll
        for (int p = 0; p < 2; ++p) load_lds16(Kbase + p*32, &Ks[0][p][kw*16][0]);
    } else {
        #pragma unroll
        for (int p = 0; p < 2; ++p) load_lds16(Vbase + p*32, &Vs[0][p][kw*16][0]);
    }

    for (int kt = 0; kt < 16; ++kt) {
        const int cur = kt & 1;
        __syncthreads();                 // staging(cur) landed; buf(1-cur) free
        if (kt + 1 < 16) {
            if (!is_v) {
                #pragma unroll
                for (int p = 0; p < 2; ++p)
                    load_lds16(Kbase + (long)(kt+1)*64*1024 + p*32, &Ks[1 - cur][p][kw*16][0]);
            } else {
                #pragma unroll
                for (int p = 0; p < 2; ++p)
                    load_lds16(Vbase + (kt+1)*64 + p*32, &Vs[1 - cur][p][kw*16][0]);
            }
        }

        // S^T[key][q] = K . Q^T ; each ak fragment shared by both q-subtiles
        floatx4 sT[2][4];
        #pragma unroll
        for (int q2 = 0; q2 < 2; ++q2)
            #pragma unroll
            for (int t = 0; t < 4; ++t) sT[q2][t] = fz;
        #pragma unroll
        for (int ks = 0; ks < 2; ++ks)
            #pragma unroll
            for (int t = 0; t < 4; ++t) {
                short8 ak = *(const short8*)&Ks[cur][ks][t*16 + sl][qd * 8];
                sT[0][t] = MFMA_BF16(ak, aq[0][ks], sT[0][t]);
                sT[1][t] = MFMA_BF16(ak, aq[1][ks], sT[1][t]);
            }

        // exp2, pack consecutive keys to bf16x2, write P^T rows (b64)
        #pragma unroll
        for (int q2 = 0; q2 < 2; ++q2)
            #pragma unroll
            for (int t = 0; t < 4; ++t) {
                const float p0 = __builtin_amdgcn_exp2f(sT[q2][t][0]);
                const float p1 = __builtin_amdgcn_exp2f(sT[q2][t][1]);
                const float p2 = __builtin_amdgcn_exp2f(sT[q2][t][2]);
                const float p3 = __builtin_amdgcn_exp2f(sT[q2][t][3]);
                l_i[q2] += (p0 + p1) + (p2 + p3);
                uint2 w;
                w.x = pack2bf(p0, p1);
                w.y = pack2bf(p2, p3);
                *(uint2*)&PT[wave][q2*16 + sl][t*16 + qd*4] = w;
            }

        // O += P V ; V fragments shared by both q-subtiles
        #pragma unroll
        for (int ks = 0; ks < 2; ++ks) {
            short8 ap0 = *(const short8*)&PT[wave][sl][ks*32 + qd*8];
            short8 ap1 = *(const short8*)&PT[wave][16 + sl][ks*32 + qd*8];
            #pragma unroll
            for (int t = 0; t < 4; ++t) {
                short8 bv = *(const short8*)&Vs[cur][ks][t*16 + sl][qd * 8];
                oacc[0][t] = MFMA_BF16(ap0, bv, oacc[0][t]);
                oacc[1][t] = MFMA_BF16(ap1, bv, oacc[1][t]);
            }
        }
    }

    // l partials: reduce over qd lane-groups; lane qd==0 writes (row, h) entry
    short* Op = ksp ? Op1 : Op0;
    #pragma unroll
    for (int q2 = 0; q2 < 2; ++q2) {
        float l = l_i[q2];
        l += __shfl_xor(l, 16);
        l += __shfl_xor(l, 32);
        if (qd == 0)
            lbuf[((long)ksp * MTOK + tok0 + q0 + wave*32 + q2*16 + sl) * 8 + h] = l;
    }

    // store UNNORMALIZED partial O (bf16)
    #pragma unroll
    for (int q2 = 0; q2 < 2; ++q2)
        #pragma unroll
        for (int t = 0; t < 4; ++t)
            #pragma unroll
            for (int r = 0; r < 4; ++r) {
                const int row = tok0 + q0 + wave*32 + q2*16 + qd*4 + r;
                const int col = h * EH + t*16 + sl;
                Op[(long)row * DM + col] = f2b(oacc[q2][t][r]);
            }
}

// ---------------------------------------------------------------------------
// Combine split-K partials: Oc = (Op0 + Op1) / (l0 + l1), all coalesced.
// Grid 2048 x 256 threads, 8 bf16 per thread (within one head slice).
// ---------------------------------------------------------------------------
__global__ __launch_bounds__(256) void attn_combine(
    const short* __restrict__ Op0, const short* __restrict__ Op1,
    const float* __restrict__ lbuf, short* __restrict__ Oc)
{
    const long idx = ((long)blockIdx.x * 256 + threadIdx.x) * 8;
    const int row = (int)(idx >> 9);
    const int h   = ((int)idx & 511) >> 6;
    const float linv = 1.0f /
        (lbuf[(long)row * 8 + h] + lbuf[((long)MTOK + row) * 8 + h]);
    short a[8], c[8], o[8];
    *(float4*)a = *(const float4*)(Op0 + idx);
    *(float4*)c = *(const float4*)(Op1 + idx);
    #pragma unroll
    for (int i = 0; i < 8; ++i)
        o[i] = f2b((b2f(a[i]) + b2f(c[i])) * linv);
    *(float4*)(Oc + idx) = *(float4*)o;
}

// ---------------------------------------------------------------------------
// out = LN(X + R) * g + beta. X fp32 or bf16, R bf16, out bf16 or fp32.
// ---------------------------------------------------------------------------
template<int X_BF16, int OUT_F32>
__global__ __launch_bounds__(256) void add_ln_kernel(
    const void* __restrict__ Xv, const short* __restrict__ R,
    const float* __restrict__ g, const float* __restrict__ beta,
    void* __restrict__ outv)
{
    const int row = blockIdx.x;
    const int tid = threadIdx.x;
    float x0, x1;
    if (X_BF16) {
        const short* xp = (const short*)Xv + (long)row * DM;
        x0 = b2f(xp[tid]); x1 = b2f(xp[tid + 256]);
    } else {
        const float* xp = (const float*)Xv + (long)row * DM;
        x0 = xp[tid]; x1 = xp[tid + 256];
    }
    const short* rp = R + (long)row * DM;
    const float v0 = x0 + b2f(rp[tid]);
    const float v1 = x1 + b2f(rp[tid + 256]);
    float s = v0 + v1, sq = v0*v0 + v1*v1;
    #pragma unroll
    for (int o = 32; o > 0; o >>= 1) {
        s  += __shfl_down(s, o);
        sq += __shfl_down(sq, o);
    }
    __shared__ float ss[4], ssq[4];
    const int wid = tid >> 6, lane = tid & 63;
    if (lane == 0) { ss[wid] = s; ssq[wid] = sq; }
    __syncthreads();
    const float S  = ss[0] + ss[1] + ss[2] + ss[3];
    const float SQ = ssq[0] + ssq[1] + ssq[2] + ssq[3];
    const float mean = S * (1.0f / DM);
    const float var  = SQ * (1.0f / DM) - mean * mean;
    const float rstd = rsqrtf(var + 1e-5f);
    const float o0 = (v0 - mean) * rstd * g[tid] + beta[tid];
    const float o1 = (v1 - mean) * rstd * g[tid + 256] + beta[tid + 256];
    if (OUT_F32) {
        float* op = (float*)outv + (long)row * DM;
        op[tid] = o0; op[tid + 256] = o1;
    } else {
        short* op = (short*)outv + (long)row * DM;
        op[tid] = f2b(o0); op[tid + 256] = f2b(o1);
    }
}

// ---------------------------------------------------------------------------
extern "C" void kernel_launch(void* const* d_in, const int* in_sizes, int n_in,
                              void* d_out, int out_size, void* d_ws, size_t ws_size,
                              hipStream_t stream)
{
    const float* x   = (const float*)d_in[0];
    const float* Wq  = (const float*)d_in[1];
    const float* bq  = (const float*)d_in[2];
    const float* Wk  = (const float*)d_in[3];
    const float* bk  = (const float*)d_in[4];
    const float* Wv  = (const float*)d_in[5];
    const float* bv  = (const float*)d_in[6];
    const float* Wo  = (const float*)d_in[7];
    const float* bo  = (const float*)d_in[8];
    const float* W1  = (const float*)d_in[9];
    const float* b1  = (const float*)d_in[10];
    const float* W2  = (const float*)d_in[11];
    const float* b2  = (const float*)d_in[12];
    const float* g1  = (const float*)d_in[13];
    const float* be1 = (const float*)d_in[14];
    const float* g2  = (const float*)d_in[15];
    const float* be2 = (const float*)d_in[16];
    float* out = (float*)d_out;

    // workspace layout (~57.1 MB)
    short* ws    = (short*)d_ws;
    short* Wqkvt = ws;                         // [1536][512]
    short* Wot   = Wqkvt + 786432;             // [512][512]
    short* W1t   = Wot + 262144;               // [2048][512]
    short* W2t   = W1t + 1048576;              // [512][2048]
    float* bqkv  = (float*)(W2t + 1048576);    // [1536] fp32
    short* xb    = (short*)(bqkv + 1536);      // [8192][512]  (later x1b)
    short* qk    = xb + 4194304;               // [8192][1024] q|k
    short* VtG   = qk + 8388608;               // [b][h][64][2048]
    short* Ob    = VtG + 4194304;              // [8192][512]  O partial 0
    short* res   = Ob + 4194304;               // [8192][512]  O partial 1 / attn_out / ffn_out
    float* lbuf  = (float*)(res + 4194304);    // [2][8192][8] fp32 (512 KB)
    short* Ocomb = qk;                         // combined O overlays dead qk
    short* hbuf  = qk;                         // [8192][2048] FFN hidden (after Wo)

    const dim3 blk(256);

    prep_kernel<<<dim3(2881), blk, 0, stream>>>(
        Wq, Wk, Wv, Wo, W1, W2, x, bq, bk, bv,
        Wqkvt, Wot, W1t, W2t, xb, bqkv);

    // QKV: [8192,512] @ [512,1536] -> qk + VtG (q scaled by QSCL)
    mfma_gemm<128, 0, 1><<<dim3(12, 64), blk, 0, stream>>>(
        xb, Wqkvt, bqkv, qk, VtG, MTOK, QKVW, DM, DM, 0);

    // split-K attention -> partial O in Ob/res, l in lbuf
    mfma_attn<<<dim3(512), dim3(512), 0, stream>>>(qk, VtG, Ob, res, lbuf);

    // combine partials -> Ocomb (qk region; q/k dead now)
    attn_combine<<<dim3(2048), blk, 0, stream>>>(Ob, res, lbuf, Ocomb);

    // Wo: [8192,512] @ [512,512] -> res (bf16), TN=64
    mfma_gemm<64, 0, 0><<<dim3(8, 64), blk, 0, stream>>>(
        Ocomb, Wot, bo, res, nullptr, MTOK, DM, DM, DM, DM);

    // x1b = LN(x + res)  (bf16)
    add_ln_kernel<0, 0><<<dim3(MTOK), blk, 0, stream>>>(x, res, g1, be1, xb);

    // FFN1: [8192,512] @ [512,2048], GELU -> hbuf
    mfma_gemm<128, 1, 0><<<dim3(16, 64), blk, 0, stream>>>(
        xb, W1t, b1, hbuf, nullptr, MTOK, DFF, DM, DM, DFF);

    // FFN2: [8192,2048] @ [2048,512] -> res, TN=64
    mfma_gemm<64, 0, 0><<<dim3(8, 64), blk, 0, stream>>>(
        hbuf, W2t, b2, res, nullptr, MTOK, DM, DFF, DFF, DM);

    // out = LN(x1b + res)  (fp32)
    add_ln_kernel<1, 1><<<dim3(MTOK), blk, 0, stream>>>(xb, res, g2, be2, out);
}